// Round 17
// baseline (1267.726 us; speedup 1.0000x reference)
//
#include <hip/hip_runtime.h>
#include <hip/hip_fp16.h>
#include <math.h>

#define BN_EPS 1e-5f
#define NBSH 7          // 128 nodes per coarse bucket
#define BKT 128
#define CAP 3072        // LDS-staged bucket capacity

__device__ __forceinline__ float4 fma4(float s, float4 a, float4 b) {
    return make_float4(fmaf(s, a.x, b.x), fmaf(s, a.y, b.y),
                       fmaf(s, a.z, b.z), fmaf(s, a.w, b.w));
}
__device__ __forceinline__ float4 add4(float4 a, float4 b) {
    return make_float4(a.x + b.x, a.y + b.y, a.z + b.z, a.w + b.w);
}
__device__ __forceinline__ float4 h4tof4(uint2 u) {
    __half2 a = *(__half2*)&u.x;
    __half2 b = *(__half2*)&u.y;
    float2 fa = __half22float2(a), fb = __half22float2(b);
    return make_float4(fa.x, fa.y, fb.x, fb.y);
}
__device__ __forceinline__ uint2 f4toh4(float4 f) {
    __half2 a = __floats2half2_rn(f.x, f.y);
    __half2 b = __floats2half2_rn(f.z, f.w);
    uint2 u;
    u.x = *(unsigned*)&a;
    u.y = *(unsigned*)&b;
    return u;
}

// ---------------- two-level counting sort: CSR by col ----------------

__global__ __launch_bounds__(1024) void chist_k(const int* __restrict__ ei,
                                                int* __restrict__ chist, int E, int NB) {
    __shared__ int h[1024];
    int t = threadIdx.x;
    for (int i = t; i < NB; i += 1024) h[i] = 0;
    __syncthreads();
    for (int e = blockIdx.x * 1024 + t; e < E; e += gridDim.x * 1024)
        atomicAdd(&h[((unsigned)ei[E + e]) >> NBSH], 1);
    __syncthreads();
    for (int i = t; i < NB; i += 1024) if (h[i]) atomicAdd(&chist[i], h[i]);
}

__global__ __launch_bounds__(1024) void cscan_k(const int* __restrict__ chist,
                                                int* __restrict__ cbase,
                                                int* __restrict__ ccur,
                                                int NB, int* __restrict__ rptrN, int E) {
    __shared__ int s[1024];
    int t = threadIdx.x;
    int v = (t < NB) ? chist[t] : 0;
    s[t] = v;
    __syncthreads();
    for (int off = 1; off < 1024; off <<= 1) {
        int x = (t >= off) ? s[t - off] : 0;
        __syncthreads();
        s[t] += x;
        __syncthreads();
    }
    int excl = s[t] - v;
    if (t < NB) { cbase[t] = excl; ccur[t] = excl; }
    if (t == 0) { cbase[NB] = E; rptrN[0] = E; }
}

__global__ __launch_bounds__(1024) void cscat_k(const int* __restrict__ ei,
                                                const float* __restrict__ ew,
                                                int* __restrict__ ccur,
                                                int2* __restrict__ pairs0, int E, int NB) {
    __shared__ int h[1024];
    __shared__ int base[1024];
    int t = threadIdx.x;
    int CH = (E + gridDim.x - 1) / gridDim.x;
    int lo = blockIdx.x * CH;
    int hi = lo + CH < E ? lo + CH : E;

    for (int i = t; i < NB; i += 1024) h[i] = 0;
    __syncthreads();
    for (int e = lo + t; e < hi; e += 1024)
        atomicAdd(&h[((unsigned)ei[E + e]) >> NBSH], 1);
    __syncthreads();
    for (int i = t; i < NB; i += 1024) {
        int c = h[i];
        base[i] = c ? atomicAdd(&ccur[i], c) : 0;
        h[i] = 0;
    }
    __syncthreads();
    for (int e = lo + t; e < hi; e += 1024) {
        int c = ei[E + e];
        int b = ((unsigned)c) >> NBSH;
        int idx = base[b] + atomicAdd(&h[b], 1);
        pairs0[idx] = make_int2(ei[e] | ((c & (BKT - 1)) << 17), __float_as_int(ew[e]));
    }
}

// fused fine pass: LDS-stage bucket, count+wsum+scan, write rptr/dinv,
// scatter (row, ew*dinv[col]); dinv[row] applied at gather time.
__global__ __launch_bounds__(256) void fineAB_k(const int2* __restrict__ pairs0,
                                                const int* __restrict__ cbase,
                                                int* __restrict__ rptr,
                                                float* __restrict__ dinv,
                                                int2* __restrict__ pairs, int N) {
    int b = blockIdx.x;
    __shared__ int2 lp[CAP];
    __shared__ int cnt[BKT];
    __shared__ float wsum[BKT];
    __shared__ int sc[256];
    __shared__ float dc[BKT];
    __shared__ int cur[BKT];
    int t = threadIdx.x;
    if (t < BKT) { cnt[t] = 0; wsum[t] = 0.f; }
    __syncthreads();
    int s = cbase[b], e = cbase[b + 1];
    int len = e - s;
    int m = len < CAP ? len : CAP;
    for (int i = t; i < m; i += 256) lp[i] = pairs0[s + i];
    __syncthreads();
    for (int i = t; i < len; i += 256) {
        int2 p = (i < m) ? lp[i] : pairs0[s + i];
        int cib = ((unsigned)p.x) >> 17;
        atomicAdd(&cnt[cib], 1);
        atomicAdd(&wsum[cib], __int_as_float(p.y));
    }
    __syncthreads();
    int v = (t < BKT) ? cnt[t] : 0;
    sc[t] = v;
    __syncthreads();
    for (int off = 1; off < 256; off <<= 1) {
        int x = (t >= off) ? sc[t - off] : 0;
        __syncthreads();
        sc[t] += x;
        __syncthreads();
    }
    int excl = sc[t] - v;
    if (t < BKT) {
        int node = b * BKT + t;
        cur[t] = s + excl;
        float dv = 1.0f / sqrtf(wsum[t] + 1.0f);
        dc[t] = dv;
        if (node < N) { rptr[node] = s + excl; dinv[node] = dv; }
    }
    __syncthreads();
    for (int i = t; i < len; i += 256) {
        int2 p = (i < m) ? lp[i] : pairs0[s + i];
        int cib = ((unsigned)p.x) >> 17;
        int row = p.x & 0x1FFFF;
        float nw = __int_as_float(p.y) * dc[cib];
        int pos = atomicAdd(&cur[cib], 1);
        pairs[pos] = make_int2(row, __float_as_int(nw));
    }
}

// ---------------- register-blocked dense matmul (R13 form: no split) ----------------
template <int DIN, int DOUT, int RPB, bool OUTH, bool WITHBN>
__global__ __launch_bounds__(256) void mm_k(const float* __restrict__ x,
                                            const float* __restrict__ w,
                                            const float* __restrict__ bias,
                                            const float* __restrict__ g,
                                            const float* __restrict__ be,
                                            const float* __restrict__ m,
                                            const float* __restrict__ v,
                                            void* __restrict__ hout, int n) {
    constexpr int XS = DIN + 4;
    constexpr int RT = 4;
    constexpr int TR = RPB / RT;
    constexpr int TC = 256 / TR;
    constexpr int CT = (DOUT / 4) / TC;
    static_assert(CT >= 1, "bad tile");
    __shared__ float xs[RPB * XS];
    __shared__ float4 ws4[DIN * (DOUT / 4)];
    int t = threadIdx.x;
    int row0 = blockIdx.x * RPB;

    for (int i = t; i < DIN * DOUT / 4; i += 256) ws4[i] = ((const float4*)w)[i];
    for (int i = t; i < RPB * DIN / 4; i += 256) {
        int r = i / (DIN / 4), kq = i % (DIN / 4);
        int gr = row0 + r;
        float4 xv = (gr < n) ? ((const float4*)x)[(size_t)gr * (DIN / 4) + kq]
                             : make_float4(0.f, 0.f, 0.f, 0.f);
        *(float4*)&xs[r * XS + kq * 4] = xv;
    }
    __syncthreads();

    int tr = t / TC;
    int tc = t % TC;
    float4 acc[RT][CT];
#pragma unroll
    for (int i = 0; i < RT; ++i)
#pragma unroll
        for (int j = 0; j < CT; ++j) acc[i][j] = make_float4(0.f, 0.f, 0.f, 0.f);

    for (int k = 0; k < DIN; k += 4) {
        float4 xv4[RT];
#pragma unroll
        for (int i = 0; i < RT; ++i)
            xv4[i] = *(const float4*)&xs[(tr * RT + i) * XS + k];
#pragma unroll
        for (int kk = 0; kk < 4; ++kk) {
#pragma unroll
            for (int j = 0; j < CT; ++j) {
                float4 wv = ws4[(k + kk) * (DOUT / 4) + tc + j * TC];
#pragma unroll
                for (int i = 0; i < RT; ++i) {
                    float xv = (kk == 0) ? xv4[i].x : (kk == 1) ? xv4[i].y
                             : (kk == 2) ? xv4[i].z : xv4[i].w;
                    acc[i][j] = fma4(xv, wv, acc[i][j]);
                }
            }
        }
    }

#pragma unroll
    for (int i = 0; i < RT; ++i) {
        int gr = row0 + tr * RT + i;
        if (gr >= n) continue;
#pragma unroll
        for (int j = 0; j < CT; ++j) {
            int c4 = tc + j * TC;
            float4 res = acc[i][j];
            if (WITHBN) {
                float4 bb = ((const float4*)bias)[c4];
                float4 gg = ((const float4*)g)[c4];
                float4 ee = ((const float4*)be)[c4];
                float4 mm = ((const float4*)m)[c4];
                float4 vv = ((const float4*)v)[c4];
                res.x = fmaxf((res.x + bb.x - mm.x) * (gg.x / sqrtf(vv.x + BN_EPS)) + ee.x, 0.f);
                res.y = fmaxf((res.y + bb.y - mm.y) * (gg.y / sqrtf(vv.y + BN_EPS)) + ee.y, 0.f);
                res.z = fmaxf((res.z + bb.z - mm.z) * (gg.z / sqrtf(vv.z + BN_EPS)) + ee.z, 0.f);
                res.w = fmaxf((res.w + bb.w - mm.w) * (gg.w / sqrtf(vv.w + BN_EPS)) + ee.w, 0.f);
            }
            if (OUTH)
                ((uint2*)hout)[(size_t)gr * (DOUT / 4) + c4] = f4toh4(res);
            else
                ((float4*)hout)[(size_t)gr * (DOUT / 4) + c4] = res;
        }
    }
}

// ---------------- layer-3 matmul: 64->128, column-split x2, RT=2, capped regs ----------------
// Per-thread: acc[2][2]=16 + xv4[2]=8 VGPR -> fits the (256,4) 64-VGPR cap without spill.
__global__ __launch_bounds__(256, 4) void mm3_k(const float* __restrict__ x,
                                                const float* __restrict__ w,
                                                const float* __restrict__ bias,
                                                const float* __restrict__ g,
                                                const float* __restrict__ be,
                                                const float* __restrict__ m,
                                                const float* __restrict__ v,
                                                float* __restrict__ hout, int n) {
    // DIN=64, DOUT=128, DOUTG=64, RPB=64, RT=2 -> TR=32, TC=8, CT=2
    __shared__ float xs[64 * 68];
    __shared__ float4 ws4[64 * 16];
    int t = threadIdx.x;
    int row0 = blockIdx.x * 64;
    int cb4 = blockIdx.y * 16;

    for (int i = t; i < 64 * 16; i += 256) {
        int kk = i >> 4, c = i & 15;
        ws4[i] = ((const float4*)w)[kk * 32 + cb4 + c];
    }
    for (int i = t; i < 64 * 16; i += 256) {
        int r = i >> 4, kq = i & 15;
        int gr = row0 + r;
        float4 xv = (gr < n) ? ((const float4*)x)[(size_t)gr * 16 + kq]
                             : make_float4(0.f, 0.f, 0.f, 0.f);
        *(float4*)&xs[r * 68 + kq * 4] = xv;
    }
    __syncthreads();

    int tr = t >> 3;   // 0..31
    int tc = t & 7;    // 0..7
    float4 acc[2][2];
#pragma unroll
    for (int i = 0; i < 2; ++i)
#pragma unroll
        for (int j = 0; j < 2; ++j) acc[i][j] = make_float4(0.f, 0.f, 0.f, 0.f);

    for (int k = 0; k < 64; k += 4) {
        float4 xv4[2];
        xv4[0] = *(const float4*)&xs[(tr * 2 + 0) * 68 + k];
        xv4[1] = *(const float4*)&xs[(tr * 2 + 1) * 68 + k];
#pragma unroll
        for (int kk = 0; kk < 4; ++kk) {
#pragma unroll
            for (int j = 0; j < 2; ++j) {
                float4 wv = ws4[(k + kk) * 16 + tc + j * 8];
#pragma unroll
                for (int i = 0; i < 2; ++i) {
                    float xv = (kk == 0) ? xv4[i].x : (kk == 1) ? xv4[i].y
                             : (kk == 2) ? xv4[i].z : xv4[i].w;
                    acc[i][j] = fma4(xv, wv, acc[i][j]);
                }
            }
        }
    }

#pragma unroll
    for (int i = 0; i < 2; ++i) {
        int gr = row0 + tr * 2 + i;
        if (gr >= n) continue;
#pragma unroll
        for (int j = 0; j < 2; ++j) {
            int c4 = cb4 + tc + j * 8;
            float4 res = acc[i][j];
            float4 bb = ((const float4*)bias)[c4];
            float4 gg = ((const float4*)g)[c4];
            float4 ee = ((const float4*)be)[c4];
            float4 mm = ((const float4*)m)[c4];
            float4 vv = ((const float4*)v)[c4];
            res.x = fmaxf((res.x + bb.x - mm.x) * (gg.x / sqrtf(vv.x + BN_EPS)) + ee.x, 0.f);
            res.y = fmaxf((res.y + bb.y - mm.y) * (gg.y / sqrtf(vv.y + BN_EPS)) + ee.y, 0.f);
            res.z = fmaxf((res.z + bb.z - mm.z) * (gg.z / sqrtf(vv.z + BN_EPS)) + ee.z, 0.f);
            res.w = fmaxf((res.w + bb.w - mm.w) * (gg.w / sqrtf(vv.w + BN_EPS)) + ee.w, 0.f);
            ((float4*)hout)[(size_t)gr * 32 + c4] = res;
        }
    }
}

// -------- 4-deep unrolled gather over fp16 rows; dinv[row] applied per edge --------
template <int TPN>
__device__ __forceinline__ float4 gather4h(const __half* __restrict__ h,
                                           const int2* __restrict__ pairs,
                                           const float* __restrict__ dinv,
                                           int s, int e, int lc) {
    const uint2* __restrict__ hb = (const uint2*)h;
    float4 a0 = make_float4(0.f, 0.f, 0.f, 0.f);
    float4 a1 = a0, a2 = a0, a3 = a0;
    int i = s;
    for (; i + 4 <= e; i += 4) {
        int2 p0 = pairs[i + 0];
        int2 p1 = pairs[i + 1];
        int2 p2 = pairs[i + 2];
        int2 p3 = pairs[i + 3];
        uint2 u0 = hb[(size_t)p0.x * TPN + lc];
        uint2 u1 = hb[(size_t)p1.x * TPN + lc];
        uint2 u2 = hb[(size_t)p2.x * TPN + lc];
        uint2 u3 = hb[(size_t)p3.x * TPN + lc];
        a0 = fma4(__int_as_float(p0.y) * dinv[p0.x], h4tof4(u0), a0);
        a1 = fma4(__int_as_float(p1.y) * dinv[p1.x], h4tof4(u1), a1);
        a2 = fma4(__int_as_float(p2.y) * dinv[p2.x], h4tof4(u2), a2);
        a3 = fma4(__int_as_float(p3.y) * dinv[p3.x], h4tof4(u3), a3);
    }
    for (; i < e; ++i) {
        int2 p = pairs[i];
        uint2 u = hb[(size_t)p.x * TPN + lc];
        a0 = fma4(__int_as_float(p.y) * dinv[p.x], h4tof4(u), a0);
    }
    return add4(add4(a0, a1), add4(a2, a3));
}

// ---------------- aggregate + bias + BN + ReLU, fp16 in, fp16 out (layer 1) ----------------
template <int D>
__global__ __launch_bounds__(256) void aggbn_k(const __half* __restrict__ h,
                                               const int* __restrict__ rptr,
                                               const int2* __restrict__ pairs,
                                               const float* __restrict__ dinv,
                                               const float* __restrict__ bias,
                                               const float* __restrict__ g,
                                               const float* __restrict__ be,
                                               const float* __restrict__ m,
                                               const float* __restrict__ v,
                                               __half* __restrict__ y, int n) {
    constexpr int TPN = D / 4;
    int npb = 256 / TPN;
    int node = blockIdx.x * npb + (int)(threadIdx.x / TPN);
    int lc = (int)(threadIdx.x % TPN);
    if (node >= n) return;

    int s = rptr[node], e = rptr[node + 1];
    float4 acc = gather4h<TPN>(h, pairs, dinv, s, e, lc);

    float dv = dinv[node];
    float sn = dv * dv;
    float4 hs = h4tof4(((const uint2*)h)[(size_t)node * TPN + lc]);
    float4 bb = ((const float4*)bias)[lc];
    float4 gg = ((const float4*)g)[lc];
    float4 ee = ((const float4*)be)[lc];
    float4 mm = ((const float4*)m)[lc];
    float4 vv = ((const float4*)v)[lc];

    float4 o;
    o.x = acc.x + sn * hs.x + bb.x;
    o.y = acc.y + sn * hs.y + bb.y;
    o.z = acc.z + sn * hs.z + bb.z;
    o.w = acc.w + sn * hs.w + bb.w;

    float4 res;
    res.x = fmaxf((o.x - mm.x) * (gg.x / sqrtf(vv.x + BN_EPS)) + ee.x, 0.f);
    res.y = fmaxf((o.y - mm.y) * (gg.y / sqrtf(vv.y + BN_EPS)) + ee.y, 0.f);
    res.z = fmaxf((o.z - mm.z) * (gg.z / sqrtf(vv.z + BN_EPS)) + ee.z, 0.f);
    res.w = fmaxf((o.w - mm.w) * (gg.w / sqrtf(vv.w + BN_EPS)) + ee.w, 0.f);

    ((uint2*)y)[(size_t)node * TPN + lc] = f4toh4(res);
}

// ---------------- aggregate, fp16 in, f32 out: z = agg + self_norm * h ----------------
template <int D>
__global__ __launch_bounds__(256) void aggpre_k(const __half* __restrict__ h,
                                                const int* __restrict__ rptr,
                                                const int2* __restrict__ pairs,
                                                const float* __restrict__ dinv,
                                                float* __restrict__ z, int n) {
    constexpr int TPN = D / 4;
    int npb = 256 / TPN;
    int node = blockIdx.x * npb + (int)(threadIdx.x / TPN);
    int lc = (int)(threadIdx.x % TPN);
    if (node >= n) return;

    int s = rptr[node], e = rptr[node + 1];
    float4 acc = gather4h<TPN>(h, pairs, dinv, s, e, lc);

    float dv = dinv[node];
    float sn = dv * dv;
    float4 hs = h4tof4(((const uint2*)h)[(size_t)node * TPN + lc]);
    acc.x = fmaf(sn, hs.x, acc.x);
    acc.y = fmaf(sn, hs.y, acc.y);
    acc.z = fmaf(sn, hs.z, acc.z);
    acc.w = fmaf(sn, hs.w, acc.w);
    ((float4*)z)[(size_t)node * TPN + lc] = acc;
}

// ---------------- parallel global mean pool (batch sorted) ----------------
__global__ __launch_bounds__(256) void pool2_k(const float* __restrict__ y,
                                               const int* __restrict__ batch,
                                               float* __restrict__ sums, int n) {
    const int NPB = 256;
    int node0 = blockIdx.x * NPB;
    int lc = threadIdx.x & 31;
    int nr = threadIdx.x >> 5;
    int end = node0 + NPB < n ? node0 + NPB : n;

    float4 acc = make_float4(0.f, 0.f, 0.f, 0.f);
    int curg = -1;
    for (int i = node0 + nr; i < end; i += 8) {
        int gph = batch[i];
        if (gph != curg) {
            if (curg >= 0) {
                float* dst = &sums[curg * 128 + lc * 4];
                atomicAdd(dst + 0, acc.x);
                atomicAdd(dst + 1, acc.y);
                atomicAdd(dst + 2, acc.z);
                atomicAdd(dst + 3, acc.w);
            }
            acc = make_float4(0.f, 0.f, 0.f, 0.f);
            curg = gph;
        }
        float4 hv = ((const float4*)y)[(size_t)i * 32 + lc];
        acc.x += hv.x; acc.y += hv.y; acc.z += hv.z; acc.w += hv.w;
    }
    if (curg >= 0) {
        float* dst = &sums[curg * 128 + lc * 4];
        atomicAdd(dst + 0, acc.x);
        atomicAdd(dst + 1, acc.y);
        atomicAdd(dst + 2, acc.z);
        atomicAdd(dst + 3, acc.w);
    }
}

// ---------------- final FCs with fused per-graph counts ----------------
__global__ __launch_bounds__(256) void fc_k(const float* __restrict__ sums,
                                            const int* __restrict__ batch, int n,
                                            const float* __restrict__ fcw,
                                            const float* __restrict__ fcb,
                                            const float* __restrict__ ow,
                                            const float* __restrict__ ob,
                                            float* __restrict__ out) {
    __shared__ float ps[64 * 128];
    __shared__ float hs[64 * 64];
    __shared__ float rc[64];
    int t = threadIdx.x;
    if (t < 64) {
        int gph = t;
        int lo = 0, hi = n;
        while (lo < hi) { int mid = (lo + hi) >> 1; if (batch[mid] < gph) lo = mid + 1; else hi = mid; }
        int s0 = lo;
        lo = 0; hi = n;
        while (lo < hi) { int mid = (lo + hi) >> 1; if (batch[mid] < gph + 1) lo = mid + 1; else hi = mid; }
        int c = lo - s0;
        rc[t] = 1.0f / (c > 0 ? (float)c : 1.0f);
    }
    __syncthreads();
    for (int i = t; i < 64 * 128; i += 256) ps[i] = sums[i] * rc[i >> 7];
    __syncthreads();
    for (int idx = t; idx < 64 * 64; idx += 256) {
        int gph = idx >> 6, j = idx & 63;
        float a = fcb[j];
        for (int k = 0; k < 128; ++k) a = fmaf(ps[gph * 128 + k], fcw[k * 64 + j], a);
        hs[idx] = fmaxf(a, 0.f);
    }
    __syncthreads();
    if (t < 64) {
        float a = ob[0];
        for (int j = 0; j < 64; ++j) a = fmaf(hs[t * 64 + j], ow[j], a);
        out[t] = a;
    }
}

extern "C" void kernel_launch(void* const* d_in, const int* in_sizes, int n_in,
                              void* d_out, int out_size, void* d_ws, size_t ws_size,
                              hipStream_t stream) {
    const float* x     = (const float*)d_in[0];
    const int*   ei    = (const int*)d_in[1];
    const float* ew    = (const float*)d_in[2];
    const int*   batch = (const int*)d_in[3];
    const float* w1 = (const float*)d_in[4],  *b1 = (const float*)d_in[5];
    const float* g1 = (const float*)d_in[6],  *be1 = (const float*)d_in[7];
    const float* m1 = (const float*)d_in[8],  *v1 = (const float*)d_in[9];
    const float* w2 = (const float*)d_in[10], *b2 = (const float*)d_in[11];
    const float* g2 = (const float*)d_in[12], *be2 = (const float*)d_in[13];
    const float* m2 = (const float*)d_in[14], *v2 = (const float*)d_in[15];
    const float* w3 = (const float*)d_in[16], *b3 = (const float*)d_in[17];
    const float* g3 = (const float*)d_in[18], *be3 = (const float*)d_in[19];
    const float* m3 = (const float*)d_in[20], *v3 = (const float*)d_in[21];
    const float* fcw = (const float*)d_in[22], *fcb = (const float*)d_in[23];
    const float* ow  = (const float*)d_in[24], *ob  = (const float*)d_in[25];
    float* out = (float*)d_out;

    const int N = in_sizes[3];
    const int E = in_sizes[2];
    const int NB = (N + BKT - 1) >> NBSH;

    // workspace layout (~116 MB):
    char* W = (char*)d_ws;
    int2*   pairs0 = (int2*)W;                          // E (dead after fineAB)
    __half* A_h    = (__half*)W;                        // N*32 (aliases pairs0)
    __half* Bf1_h  = (__half*)(W + (size_t)N * 32 * 2); // N*32 (aliases pairs0)
    float*  z      = (float*)(W + (size_t)E * 8);       // N*32 f32
    float*  z2     = z + (size_t)N * 32;                // N*64 f32
    float*  Y      = z2 + (size_t)N * 64;               // N*128 f32
    __half* Bf2_h  = (__half*)Y;                        // N*64 (dead before Y written)
    float*  dinv   = Y + (size_t)N * 128;               // N
    int*    rptr   = (int*)(dinv + N);                  // N+1
    int*    chist  = rptr + (N + 1);                    // NB
    float*  sums   = (float*)(chist + NB);              // 64*128
    int*    cbase  = (int*)(sums + 64 * 128);           // NB+1
    int*    ccur   = cbase + NB + 1;                    // NB
    int2*   pairs  = (int2*)(ccur + NB);                // E

    hipMemsetAsync(chist, 0, (NB + 64 * 128) * sizeof(int), stream);

    chist_k<<<256, 1024, 0, stream>>>(ei, chist, E, NB);
    cscan_k<<<1, 1024, 0, stream>>>(chist, cbase, ccur, NB, rptr + N, E);
    cscat_k<<<256, 1024, 0, stream>>>(ei, ew, ccur, pairs0, E, NB);
    fineAB_k<<<NB, 256, 0, stream>>>(pairs0, cbase, rptr, dinv, pairs, N);

    // layer 1: matmul 64->32 (fp16 out), aggregate+BN+ReLU (fp16 out)
    mm_k<64, 32, 128, true, false><<<(N + 127) / 128, 256, 0, stream>>>(
        x, w1, nullptr, nullptr, nullptr, nullptr, nullptr, A_h, N);
    aggbn_k<32><<<(N + 31) / 32, 256, 0, stream>>>(A_h, rptr, pairs, dinv,
                                                   b1, g1, be1, m1, v1, Bf1_h, N);
    // layer 2: aggregate (fp16 in, f32 out), matmul 32->64 +BN (fp16 out)
    aggpre_k<32><<<(N + 31) / 32, 256, 0, stream>>>(Bf1_h, rptr, pairs, dinv, z, N);
    mm_k<32, 64, 64, true, true><<<(N + 63) / 64, 256, 0, stream>>>(
        z, w2, b2, g2, be2, m2, v2, Bf2_h, N);
    // layer 3: aggregate (fp16 in, f32 out), matmul 64->128 +BN (f32 out), split x2
    aggpre_k<64><<<(N + 15) / 16, 256, 0, stream>>>(Bf2_h, rptr, pairs, dinv, z2, N);
    mm3_k<<<dim3((N + 63) / 64, 2), 256, 0, stream>>>(
        z2, w3, b3, g3, be3, m3, v3, Y, N);

    pool2_k<<<(N + 255) / 256, 256, 0, stream>>>(Y, batch, sums, N);
    fc_k<<<1, 256, 0, stream>>>(sums, batch, N, fcw, fcb, ow, ob, out);
}

// Round 18
// 313.251 us; speedup vs baseline: 4.0470x; 4.0470x over previous
//
#include <hip/hip_runtime.h>
#include <hip/hip_fp16.h>
#include <math.h>

#define BN_EPS 1e-5f
#define NBSH 7          // 128 nodes per coarse bucket
#define BKT 128
#define CAP 3072        // LDS-staged bucket capacity

__device__ __forceinline__ float4 fma4(float s, float4 a, float4 b) {
    return make_float4(fmaf(s, a.x, b.x), fmaf(s, a.y, b.y),
                       fmaf(s, a.z, b.z), fmaf(s, a.w, b.w));
}
__device__ __forceinline__ float4 add4(float4 a, float4 b) {
    return make_float4(a.x + b.x, a.y + b.y, a.z + b.z, a.w + b.w);
}
__device__ __forceinline__ float4 h4tof4(uint2 u) {
    __half2 a = *(__half2*)&u.x;
    __half2 b = *(__half2*)&u.y;
    float2 fa = __half22float2(a), fb = __half22float2(b);
    return make_float4(fa.x, fa.y, fb.x, fb.y);
}
__device__ __forceinline__ uint2 f4toh4(float4 f) {
    __half2 a = __floats2half2_rn(f.x, f.y);
    __half2 b = __floats2half2_rn(f.z, f.w);
    uint2 u;
    u.x = *(unsigned*)&a;
    u.y = *(unsigned*)&b;
    return u;
}

// ---------------- two-level counting sort: CSR by col ----------------

__global__ __launch_bounds__(1024) void chist_k(const int* __restrict__ ei,
                                                int* __restrict__ chist, int E, int NB) {
    __shared__ int h[1024];
    int t = threadIdx.x;
    for (int i = t; i < NB; i += 1024) h[i] = 0;
    __syncthreads();
    for (int e = blockIdx.x * 1024 + t; e < E; e += gridDim.x * 1024)
        atomicAdd(&h[((unsigned)ei[E + e]) >> NBSH], 1);
    __syncthreads();
    for (int i = t; i < NB; i += 1024) if (h[i]) atomicAdd(&chist[i], h[i]);
}

__global__ __launch_bounds__(1024) void cscan_k(const int* __restrict__ chist,
                                                int* __restrict__ cbase,
                                                int* __restrict__ ccur,
                                                int NB, int* __restrict__ rptrN, int E) {
    __shared__ int s[1024];
    int t = threadIdx.x;
    int v = (t < NB) ? chist[t] : 0;
    s[t] = v;
    __syncthreads();
    for (int off = 1; off < 1024; off <<= 1) {
        int x = (t >= off) ? s[t - off] : 0;
        __syncthreads();
        s[t] += x;
        __syncthreads();
    }
    int excl = s[t] - v;
    if (t < NB) { cbase[t] = excl; ccur[t] = excl; }
    if (t == 0) { cbase[NB] = E; rptrN[0] = E; }
}

__global__ __launch_bounds__(1024) void cscat_k(const int* __restrict__ ei,
                                                const float* __restrict__ ew,
                                                int* __restrict__ ccur,
                                                int2* __restrict__ pairs0, int E, int NB) {
    __shared__ int h[1024];
    __shared__ int base[1024];
    int t = threadIdx.x;
    int CH = (E + gridDim.x - 1) / gridDim.x;
    int lo = blockIdx.x * CH;
    int hi = lo + CH < E ? lo + CH : E;

    for (int i = t; i < NB; i += 1024) h[i] = 0;
    __syncthreads();
    for (int e = lo + t; e < hi; e += 1024)
        atomicAdd(&h[((unsigned)ei[E + e]) >> NBSH], 1);
    __syncthreads();
    for (int i = t; i < NB; i += 1024) {
        int c = h[i];
        base[i] = c ? atomicAdd(&ccur[i], c) : 0;
        h[i] = 0;
    }
    __syncthreads();
    for (int e = lo + t; e < hi; e += 1024) {
        int c = ei[E + e];
        int b = ((unsigned)c) >> NBSH;
        int idx = base[b] + atomicAdd(&h[b], 1);
        pairs0[idx] = make_int2(ei[e] | ((c & (BKT - 1)) << 17), __float_as_int(ew[e]));
    }
}

// fused fine pass: LDS-stage bucket, count+wsum+scan, write rptr/dinv,
// scatter (row, ew*dinv[col]); dinv[row] applied at gather time.
__global__ __launch_bounds__(256) void fineAB_k(const int2* __restrict__ pairs0,
                                                const int* __restrict__ cbase,
                                                int* __restrict__ rptr,
                                                float* __restrict__ dinv,
                                                int2* __restrict__ pairs, int N) {
    int b = blockIdx.x;
    __shared__ int2 lp[CAP];
    __shared__ int cnt[BKT];
    __shared__ float wsum[BKT];
    __shared__ int sc[256];
    __shared__ float dc[BKT];
    __shared__ int cur[BKT];
    int t = threadIdx.x;
    if (t < BKT) { cnt[t] = 0; wsum[t] = 0.f; }
    __syncthreads();
    int s = cbase[b], e = cbase[b + 1];
    int len = e - s;
    int m = len < CAP ? len : CAP;
    for (int i = t; i < m; i += 256) lp[i] = pairs0[s + i];
    __syncthreads();
    for (int i = t; i < len; i += 256) {
        int2 p = (i < m) ? lp[i] : pairs0[s + i];
        int cib = ((unsigned)p.x) >> 17;
        atomicAdd(&cnt[cib], 1);
        atomicAdd(&wsum[cib], __int_as_float(p.y));
    }
    __syncthreads();
    int v = (t < BKT) ? cnt[t] : 0;
    sc[t] = v;
    __syncthreads();
    for (int off = 1; off < 256; off <<= 1) {
        int x = (t >= off) ? sc[t - off] : 0;
        __syncthreads();
        sc[t] += x;
        __syncthreads();
    }
    int excl = sc[t] - v;
    if (t < BKT) {
        int node = b * BKT + t;
        cur[t] = s + excl;
        float dv = 1.0f / sqrtf(wsum[t] + 1.0f);
        dc[t] = dv;
        if (node < N) { rptr[node] = s + excl; dinv[node] = dv; }
    }
    __syncthreads();
    for (int i = t; i < len; i += 256) {
        int2 p = (i < m) ? lp[i] : pairs0[s + i];
        int cib = ((unsigned)p.x) >> 17;
        int row = p.x & 0x1FFFF;
        float nw = __int_as_float(p.y) * dc[cib];
        int pos = atomicAdd(&cur[cib], 1);
        pairs[pos] = make_int2(row, __float_as_int(nw));
    }
}

// ---------------- register-blocked dense matmul ----------------
// Interleaved column mapping (tc + j*TC) keeps ds_read_b128 bank-conflict-free.
template <int DIN, int DOUT, int RPB, bool OUTH, bool WITHBN>
__global__ __launch_bounds__(256) void mm_k(const float* __restrict__ x,
                                            const float* __restrict__ w,
                                            const float* __restrict__ bias,
                                            const float* __restrict__ g,
                                            const float* __restrict__ be,
                                            const float* __restrict__ m,
                                            const float* __restrict__ v,
                                            void* __restrict__ hout, int n) {
    constexpr int XS = DIN + 4;
    constexpr int RT = 4;
    constexpr int TR = RPB / RT;
    constexpr int TC = 256 / TR;
    constexpr int CT = (DOUT / 4) / TC;
    static_assert(CT >= 1, "bad tile");
    __shared__ float xs[RPB * XS];
    __shared__ float4 ws4[DIN * (DOUT / 4)];
    int t = threadIdx.x;
    int row0 = blockIdx.x * RPB;

    for (int i = t; i < DIN * DOUT / 4; i += 256) ws4[i] = ((const float4*)w)[i];
    for (int i = t; i < RPB * DIN / 4; i += 256) {
        int r = i / (DIN / 4), kq = i % (DIN / 4);
        int gr = row0 + r;
        float4 xv = (gr < n) ? ((const float4*)x)[(size_t)gr * (DIN / 4) + kq]
                             : make_float4(0.f, 0.f, 0.f, 0.f);
        *(float4*)&xs[r * XS + kq * 4] = xv;
    }
    __syncthreads();

    int tr = t / TC;
    int tc = t % TC;
    float4 acc[RT][CT];
#pragma unroll
    for (int i = 0; i < RT; ++i)
#pragma unroll
        for (int j = 0; j < CT; ++j) acc[i][j] = make_float4(0.f, 0.f, 0.f, 0.f);

    for (int k = 0; k < DIN; ++k) {
        float xv[RT];
#pragma unroll
        for (int i = 0; i < RT; ++i) xv[i] = xs[(tr * RT + i) * XS + k];
#pragma unroll
        for (int j = 0; j < CT; ++j) {
            float4 wv = ws4[k * (DOUT / 4) + tc + j * TC];
#pragma unroll
            for (int i = 0; i < RT; ++i) acc[i][j] = fma4(xv[i], wv, acc[i][j]);
        }
    }

#pragma unroll
    for (int i = 0; i < RT; ++i) {
        int gr = row0 + tr * RT + i;
        if (gr >= n) continue;
#pragma unroll
        for (int j = 0; j < CT; ++j) {
            int c4 = tc + j * TC;
            float4 res = acc[i][j];
            if (WITHBN) {
                float4 bb = ((const float4*)bias)[c4];
                float4 gg = ((const float4*)g)[c4];
                float4 ee = ((const float4*)be)[c4];
                float4 mm = ((const float4*)m)[c4];
                float4 vv = ((const float4*)v)[c4];
                res.x = fmaxf((res.x + bb.x - mm.x) * (gg.x / sqrtf(vv.x + BN_EPS)) + ee.x, 0.f);
                res.y = fmaxf((res.y + bb.y - mm.y) * (gg.y / sqrtf(vv.y + BN_EPS)) + ee.y, 0.f);
                res.z = fmaxf((res.z + bb.z - mm.z) * (gg.z / sqrtf(vv.z + BN_EPS)) + ee.z, 0.f);
                res.w = fmaxf((res.w + bb.w - mm.w) * (gg.w / sqrtf(vv.w + BN_EPS)) + ee.w, 0.f);
            }
            if (OUTH)
                ((uint2*)hout)[(size_t)gr * (DOUT / 4) + c4] = f4toh4(res);
            else
                ((float4*)hout)[(size_t)gr * (DOUT / 4) + c4] = res;
        }
    }
}

// -------- 4-deep unrolled gather over fp16 rows; dinv[row] applied per edge --------
template <int TPN>
__device__ __forceinline__ float4 gather4h(const __half* __restrict__ h,
                                           const int2* __restrict__ pairs,
                                           const float* __restrict__ dinv,
                                           int s, int e, int lc) {
    const uint2* __restrict__ hb = (const uint2*)h;
    float4 a0 = make_float4(0.f, 0.f, 0.f, 0.f);
    float4 a1 = a0, a2 = a0, a3 = a0;
    int i = s;
    for (; i + 4 <= e; i += 4) {
        int2 p0 = pairs[i + 0];
        int2 p1 = pairs[i + 1];
        int2 p2 = pairs[i + 2];
        int2 p3 = pairs[i + 3];
        uint2 u0 = hb[(size_t)p0.x * TPN + lc];
        uint2 u1 = hb[(size_t)p1.x * TPN + lc];
        uint2 u2 = hb[(size_t)p2.x * TPN + lc];
        uint2 u3 = hb[(size_t)p3.x * TPN + lc];
        a0 = fma4(__int_as_float(p0.y) * dinv[p0.x], h4tof4(u0), a0);
        a1 = fma4(__int_as_float(p1.y) * dinv[p1.x], h4tof4(u1), a1);
        a2 = fma4(__int_as_float(p2.y) * dinv[p2.x], h4tof4(u2), a2);
        a3 = fma4(__int_as_float(p3.y) * dinv[p3.x], h4tof4(u3), a3);
    }
    for (; i < e; ++i) {
        int2 p = pairs[i];
        uint2 u = hb[(size_t)p.x * TPN + lc];
        a0 = fma4(__int_as_float(p.y) * dinv[p.x], h4tof4(u), a0);
    }
    return add4(add4(a0, a1), add4(a2, a3));
}

// ---------------- aggregate + bias + BN + ReLU, fp16 in, fp16 out (layer 1) ----------------
template <int D>
__global__ __launch_bounds__(256) void aggbn_k(const __half* __restrict__ h,
                                               const int* __restrict__ rptr,
                                               const int2* __restrict__ pairs,
                                               const float* __restrict__ dinv,
                                               const float* __restrict__ bias,
                                               const float* __restrict__ g,
                                               const float* __restrict__ be,
                                               const float* __restrict__ m,
                                               const float* __restrict__ v,
                                               __half* __restrict__ y, int n) {
    constexpr int TPN = D / 4;
    int npb = 256 / TPN;
    int node = blockIdx.x * npb + (int)(threadIdx.x / TPN);
    int lc = (int)(threadIdx.x % TPN);
    if (node >= n) return;

    int s = rptr[node], e = rptr[node + 1];
    float4 acc = gather4h<TPN>(h, pairs, dinv, s, e, lc);

    float dv = dinv[node];
    float sn = dv * dv;
    float4 hs = h4tof4(((const uint2*)h)[(size_t)node * TPN + lc]);
    float4 bb = ((const float4*)bias)[lc];
    float4 gg = ((const float4*)g)[lc];
    float4 ee = ((const float4*)be)[lc];
    float4 mm = ((const float4*)m)[lc];
    float4 vv = ((const float4*)v)[lc];

    float4 o;
    o.x = acc.x + sn * hs.x + bb.x;
    o.y = acc.y + sn * hs.y + bb.y;
    o.z = acc.z + sn * hs.z + bb.z;
    o.w = acc.w + sn * hs.w + bb.w;

    float4 res;
    res.x = fmaxf((o.x - mm.x) * (gg.x / sqrtf(vv.x + BN_EPS)) + ee.x, 0.f);
    res.y = fmaxf((o.y - mm.y) * (gg.y / sqrtf(vv.y + BN_EPS)) + ee.y, 0.f);
    res.z = fmaxf((o.z - mm.z) * (gg.z / sqrtf(vv.z + BN_EPS)) + ee.z, 0.f);
    res.w = fmaxf((o.w - mm.w) * (gg.w / sqrtf(vv.w + BN_EPS)) + ee.w, 0.f);

    ((uint2*)y)[(size_t)node * TPN + lc] = f4toh4(res);
}

// ---------------- aggregate, fp16 in, f32 out: z = agg + self_norm * h ----------------
template <int D>
__global__ __launch_bounds__(256) void aggpre_k(const __half* __restrict__ h,
                                                const int* __restrict__ rptr,
                                                const int2* __restrict__ pairs,
                                                const float* __restrict__ dinv,
                                                float* __restrict__ z, int n) {
    constexpr int TPN = D / 4;
    int npb = 256 / TPN;
    int node = blockIdx.x * npb + (int)(threadIdx.x / TPN);
    int lc = (int)(threadIdx.x % TPN);
    if (node >= n) return;

    int s = rptr[node], e = rptr[node + 1];
    float4 acc = gather4h<TPN>(h, pairs, dinv, s, e, lc);

    float dv = dinv[node];
    float sn = dv * dv;
    float4 hs = h4tof4(((const uint2*)h)[(size_t)node * TPN + lc]);
    acc.x = fmaf(sn, hs.x, acc.x);
    acc.y = fmaf(sn, hs.y, acc.y);
    acc.z = fmaf(sn, hs.z, acc.z);
    acc.w = fmaf(sn, hs.w, acc.w);
    ((float4*)z)[(size_t)node * TPN + lc] = acc;
}

// ---------------- parallel global mean pool (batch sorted) ----------------
__global__ __launch_bounds__(256) void pool2_k(const float* __restrict__ y,
                                               const int* __restrict__ batch,
                                               float* __restrict__ sums, int n) {
    const int NPB = 256;
    int node0 = blockIdx.x * NPB;
    int lc = threadIdx.x & 31;
    int nr = threadIdx.x >> 5;
    int end = node0 + NPB < n ? node0 + NPB : n;

    float4 acc = make_float4(0.f, 0.f, 0.f, 0.f);
    int curg = -1;
    for (int i = node0 + nr; i < end; i += 8) {
        int gph = batch[i];
        if (gph != curg) {
            if (curg >= 0) {
                float* dst = &sums[curg * 128 + lc * 4];
                atomicAdd(dst + 0, acc.x);
                atomicAdd(dst + 1, acc.y);
                atomicAdd(dst + 2, acc.z);
                atomicAdd(dst + 3, acc.w);
            }
            acc = make_float4(0.f, 0.f, 0.f, 0.f);
            curg = gph;
        }
        float4 hv = ((const float4*)y)[(size_t)i * 32 + lc];
        acc.x += hv.x; acc.y += hv.y; acc.z += hv.z; acc.w += hv.w;
    }
    if (curg >= 0) {
        float* dst = &sums[curg * 128 + lc * 4];
        atomicAdd(dst + 0, acc.x);
        atomicAdd(dst + 1, acc.y);
        atomicAdd(dst + 2, acc.z);
        atomicAdd(dst + 3, acc.w);
    }
}

// ---------------- final FCs with fused per-graph counts ----------------
__global__ __launch_bounds__(256) void fc_k(const float* __restrict__ sums,
                                            const int* __restrict__ batch, int n,
                                            const float* __restrict__ fcw,
                                            const float* __restrict__ fcb,
                                            const float* __restrict__ ow,
                                            const float* __restrict__ ob,
                                            float* __restrict__ out) {
    __shared__ float ps[64 * 128];
    __shared__ float hs[64 * 64];
    __shared__ float rc[64];
    int t = threadIdx.x;
    if (t < 64) {
        int gph = t;
        int lo = 0, hi = n;
        while (lo < hi) { int mid = (lo + hi) >> 1; if (batch[mid] < gph) lo = mid + 1; else hi = mid; }
        int s0 = lo;
        lo = 0; hi = n;
        while (lo < hi) { int mid = (lo + hi) >> 1; if (batch[mid] < gph + 1) lo = mid + 1; else hi = mid; }
        int c = lo - s0;
        rc[t] = 1.0f / (c > 0 ? (float)c : 1.0f);
    }
    __syncthreads();
    for (int i = t; i < 64 * 128; i += 256) ps[i] = sums[i] * rc[i >> 7];
    __syncthreads();
    for (int idx = t; idx < 64 * 64; idx += 256) {
        int gph = idx >> 6, j = idx & 63;
        float a = fcb[j];
        for (int k = 0; k < 128; ++k) a = fmaf(ps[gph * 128 + k], fcw[k * 64 + j], a);
        hs[idx] = fmaxf(a, 0.f);
    }
    __syncthreads();
    if (t < 64) {
        float a = ob[0];
        for (int j = 0; j < 64; ++j) a = fmaf(hs[t * 64 + j], ow[j], a);
        out[t] = a;
    }
}

extern "C" void kernel_launch(void* const* d_in, const int* in_sizes, int n_in,
                              void* d_out, int out_size, void* d_ws, size_t ws_size,
                              hipStream_t stream) {
    const float* x     = (const float*)d_in[0];
    const int*   ei    = (const int*)d_in[1];
    const float* ew    = (const float*)d_in[2];
    const int*   batch = (const int*)d_in[3];
    const float* w1 = (const float*)d_in[4],  *b1 = (const float*)d_in[5];
    const float* g1 = (const float*)d_in[6],  *be1 = (const float*)d_in[7];
    const float* m1 = (const float*)d_in[8],  *v1 = (const float*)d_in[9];
    const float* w2 = (const float*)d_in[10], *b2 = (const float*)d_in[11];
    const float* g2 = (const float*)d_in[12], *be2 = (const float*)d_in[13];
    const float* m2 = (const float*)d_in[14], *v2 = (const float*)d_in[15];
    const float* w3 = (const float*)d_in[16], *b3 = (const float*)d_in[17];
    const float* g3 = (const float*)d_in[18], *be3 = (const float*)d_in[19];
    const float* m3 = (const float*)d_in[20], *v3 = (const float*)d_in[21];
    const float* fcw = (const float*)d_in[22], *fcb = (const float*)d_in[23];
    const float* ow  = (const float*)d_in[24], *ob  = (const float*)d_in[25];
    float* out = (float*)d_out;

    const int N = in_sizes[3];
    const int E = in_sizes[2];
    const int NB = (N + BKT - 1) >> NBSH;

    // workspace layout (~116 MB):
    char* W = (char*)d_ws;
    int2*   pairs0 = (int2*)W;                          // E (dead after fineAB)
    __half* A_h    = (__half*)W;                        // N*32 (aliases pairs0)
    __half* Bf1_h  = (__half*)(W + (size_t)N * 32 * 2); // N*32 (aliases pairs0)
    float*  z      = (float*)(W + (size_t)E * 8);       // N*32 f32
    float*  z2     = z + (size_t)N * 32;                // N*64 f32
    float*  Y      = z2 + (size_t)N * 64;               // N*128 f32
    __half* Bf2_h  = (__half*)Y;                        // N*64 (dead before Y written)
    float*  dinv   = Y + (size_t)N * 128;               // N
    int*    rptr   = (int*)(dinv + N);                  // N+1
    int*    chist  = rptr + (N + 1);                    // NB
    float*  sums   = (float*)(chist + NB);              // 64*128
    int*    cbase  = (int*)(sums + 64 * 128);           // NB+1
    int*    ccur   = cbase + NB + 1;                    // NB
    int2*   pairs  = (int2*)(ccur + NB);                // E

    hipMemsetAsync(chist, 0, (NB + 64 * 128) * sizeof(int), stream);

    chist_k<<<256, 1024, 0, stream>>>(ei, chist, E, NB);
    cscan_k<<<1, 1024, 0, stream>>>(chist, cbase, ccur, NB, rptr + N, E);
    cscat_k<<<256, 1024, 0, stream>>>(ei, ew, ccur, pairs0, E, NB);
    fineAB_k<<<NB, 256, 0, stream>>>(pairs0, cbase, rptr, dinv, pairs, N);

    // layer 1: matmul 64->32 (fp16 out), aggregate+BN+ReLU (fp16 out)
    mm_k<64, 32, 128, true, false><<<(N + 127) / 128, 256, 0, stream>>>(
        x, w1, nullptr, nullptr, nullptr, nullptr, nullptr, A_h, N);
    aggbn_k<32><<<(N + 31) / 32, 256, 0, stream>>>(A_h, rptr, pairs, dinv,
                                                   b1, g1, be1, m1, v1, Bf1_h, N);
    // layer 2: aggregate (fp16 in, f32 out), matmul 32->64 +BN (fp16 out)
    aggpre_k<32><<<(N + 31) / 32, 256, 0, stream>>>(Bf1_h, rptr, pairs, dinv, z, N);
    mm_k<32, 64, 64, true, true><<<(N + 63) / 64, 256, 0, stream>>>(
        z, w2, b2, g2, be2, m2, v2, Bf2_h, N);
    // layer 3: aggregate (fp16 in, f32 out), matmul 64->128 +BN (f32 out)
    aggpre_k<64><<<(N + 15) / 16, 256, 0, stream>>>(Bf2_h, rptr, pairs, dinv, z2, N);
    mm_k<64, 128, 64, false, true><<<(N + 63) / 64, 256, 0, stream>>>(
        z2, w3, b3, g3, be3, m3, v3, Y, N);

    pool2_k<<<(N + 255) / 256, 256, 0, stream>>>(Y, batch, sums, N);
    fc_k<<<1, 256, 0, stream>>>(sums, batch, N, fcw, fcb, ow, ob, out);
}